// Round 11
// baseline (133.915 us; speedup 1.0000x reference)
//
#include <hip/hip_runtime.h>
#include <math.h>

#define BB 2
#define TT 512
#define UU 48
#define DD 512
#define HH 1024
#define KK 128

typedef _Float16 f16x8 __attribute__((ext_vector_type(8)));
typedef __fp16 fp16x2_t __attribute__((ext_vector_type(2)));
typedef float floatx4 __attribute__((ext_vector_type(4)));
typedef float floatx16 __attribute__((ext_vector_type(16)));

// async 16B/lane global->LDS (dest: wave-uniform base + lane*16)
__device__ __forceinline__ void g2l16(const _Float16* g, _Float16* l) {
    __builtin_amdgcn_global_load_lds(
        (const __attribute__((address_space(1))) unsigned int*)g,
        (__attribute__((address_space(3))) unsigned int*)l, 16, 0, 0);
}

// tanh(x) = 1 - 2/(e^{2x}+1). Safe at +-inf (no clamp).
__device__ __forceinline__ f16x8 tanh8(f16x8 x) {
    f16x8 o;
#pragma unroll
    for (int i = 0; i < 8; i += 2) {
        float s0 = (float)x[i];
        float s1 = (float)x[i + 1];
        float e0 = __expf(s0 + s0);
        float e1 = __expf(s1 + s1);
        float r0 = __builtin_amdgcn_rcpf(e0 + 1.0f);
        float r1 = __builtin_amdgcn_rcpf(e1 + 1.0f);
        fp16x2_t p = __builtin_amdgcn_cvt_pkrtz(fmaf(-2.0f, r0, 1.0f),
                                                fmaf(-2.0f, r1, 1.0f));
        o[i] = (_Float16)p[0];
        o[i + 1] = (_Float16)p[1];
    }
    return o;
}

// ---------------- mid: imgH/labH/seg GEMMs + W2 swizzle, one dispatch -------
__global__ __launch_bounds__(256) void mid_kernel4(
    const float* __restrict__ img, const float* __restrict__ labf,
    const float* __restrict__ W1, const float* __restrict__ W2,
    const float* __restrict__ conv_w,
    const float* __restrict__ b1, const float* __restrict__ conv_b,
    const float* __restrict__ masks,
    _Float16* __restrict__ imgHf, _Float16* __restrict__ labHf,
    _Float16* __restrict__ W2s, float* __restrict__ seg_out) {
    int bid = blockIdx.x, tid = threadIdx.x;
    if (bid >= 312) {  // W2 swizzle: W2s[(h>>3)*1024 + k*8 + (h&7)] = W2[k][h]
        int base = (bid - 312) * 256 + tid;
#pragma unroll
        for (int i = 0; i < 32; ++i) {
            int o = base + i * 4096;
            int hg = o >> 10, kk2 = (o >> 3) & 127, hl = o & 7;
            W2s[o] = (_Float16)W2[(size_t)kk2 * HH + hg * 8 + hl];
        }
        return;
    }
    __shared__ __align__(16) _Float16 a_s[32][72];
    __shared__ __align__(16) _Float16 w_s[8192];
    const float* Arow;
    const float* Wbase;
    int r0, n0b, wstride, region;
    if (bid < 256) {
        region = 0; Arow = img; Wbase = W1 + 512; wstride = 1024;
        r0 = (bid & 31) * 32; n0b = (bid >> 5) * 128;
    } else if (bid < 280) {
        region = 1; Arow = labf; Wbase = W1; wstride = 1024;
        int i = bid - 256; r0 = (i % 3) * 32; n0b = (i / 3) * 128;
    } else {
        region = 2; Arow = img; Wbase = conv_w; wstride = 512;
        r0 = (bid - 280) * 32; n0b = 0;
    }
    int lane = tid & 63, wv = tid >> 6;
    int m0 = (wv & 1) * 16, n0w = (wv >> 1) * 64;
    int q = lane >> 4, r = lane & 15;
    int arow = tid >> 3, acol = (tid & 7) * 8;
    int wn = tid >> 3, wk = tid & 7;
    const float* aptr = &Arow[(size_t)(r0 + arow) * DD + acol];
    floatx4 acc[4] = {};
    float4 pa0, pa1, pw[4][2];
    pa0 = *(const float4*)aptr;
    pa1 = *(const float4*)(aptr + 4);
#pragma unroll
    for (int i2 = 0; i2 < 4; ++i2) {
        const float* wp_ = &Wbase[(size_t)(n0b + i2 * 32 + wn) * wstride + wk * 8];
        pw[i2][0] = *(const float4*)wp_;
        pw[i2][1] = *(const float4*)(wp_ + 4);
    }
    for (int c = 0; c < 8; ++c) {
        {
            f16x8 av;
            av[0] = (_Float16)pa0.x; av[1] = (_Float16)pa0.y;
            av[2] = (_Float16)pa0.z; av[3] = (_Float16)pa0.w;
            av[4] = (_Float16)pa1.x; av[5] = (_Float16)pa1.y;
            av[6] = (_Float16)pa1.z; av[7] = (_Float16)pa1.w;
            *(f16x8*)&a_s[arow][acol] = av;
#pragma unroll
            for (int i2 = 0; i2 < 4; ++i2) {
                f16x8 wvv;
                wvv[0] = (_Float16)pw[i2][0].x; wvv[1] = (_Float16)pw[i2][0].y;
                wvv[2] = (_Float16)pw[i2][0].z; wvv[3] = (_Float16)pw[i2][0].w;
                wvv[4] = (_Float16)pw[i2][1].x; wvv[5] = (_Float16)pw[i2][1].y;
                wvv[6] = (_Float16)pw[i2][1].z; wvv[7] = (_Float16)pw[i2][1].w;
                *(f16x8*)&w_s[((size_t)wk * 128 + i2 * 32 + wn) * 8] = wvv;
            }
        }
        __syncthreads();
        if (c < 7) {
            int cb = (c + 1) * 64;
            pa0 = *(const float4*)(aptr + cb);
            pa1 = *(const float4*)(aptr + cb + 4);
#pragma unroll
            for (int i2 = 0; i2 < 4; ++i2) {
                const float* wp_ =
                    &Wbase[(size_t)(n0b + i2 * 32 + wn) * wstride + cb + wk * 8];
                pw[i2][0] = *(const float4*)wp_;
                pw[i2][1] = *(const float4*)(wp_ + 4);
            }
        }
#pragma unroll
        for (int kt = 0; kt < 2; ++kt) {
            f16x8 af = *(const f16x8*)&a_s[m0 + r][kt * 32 + q * 8];
#pragma unroll
            for (int nt = 0; nt < 4; ++nt) {
                f16x8 bfv = *(const f16x8*)
                    &w_s[((kt * 4 + q) * 128 + n0w + nt * 16 + r) * 8];
                acc[nt] = __builtin_amdgcn_mfma_f32_16x16x32_f16(
                    af, bfv, acc[nt], 0, 0, 0);
            }
        }
        __syncthreads();
    }
    if (region == 0) {
#pragma unroll
        for (int nt = 0; nt < 4; ++nt) {
            int n = n0b + n0w + nt * 16 + r;
#pragma unroll
            for (int rr = 0; rr < 4; ++rr)
                imgHf[(size_t)(r0 + m0 + 4 * q + rr) * HH + n] =
                    (_Float16)acc[nt][rr];
        }
    } else if (region == 1) {
#pragma unroll
        for (int nt = 0; nt < 4; ++nt) {
            int n = n0b + n0w + nt * 16 + r;
            float bv = b1[n];
#pragma unroll
            for (int rr = 0; rr < 4; ++rr)
                labHf[(size_t)(r0 + m0 + 4 * q + rr) * HH + n] =
                    (_Float16)(acc[nt][rr] + bv);
        }
    } else {
#pragma unroll
        for (int nt = 0; nt < 4; ++nt) {
            int k = n0w + nt * 16 + r;
            float bv = conv_b[k];
#pragma unroll
            for (int rr = 0; rr < 4; ++rr) {
                int row = r0 + m0 + 4 * q + rr;
                int b = row >> 9, t = row & 511;
                seg_out[((size_t)b * KK + k) * TT + t] =
                    (acc[nt][rr] + bv) * masks[row];
            }
        }
    }
}

// ---------------- joint: 32x32x16 MFMA, 2 waves/block (32 rows/wave), zero-LDS
// h into A-frags, dbuf W2 via async global_load_lds, in-register log-softmax.
// A: m=lane&31, k=(lane>>5)*8+j.  B: n=lane&31, k=(lane>>5)*8+j.
// C/D: col=lane&31, row=(reg&3)+8*(reg>>2)+4*(lane>>5)  [m101-verified]
__global__ __launch_bounds__(128, 2) void joint_kernel9(
    const _Float16* __restrict__ imgHf,  // [B*T][H]
    const _Float16* __restrict__ labHf,  // [B*U][H] (b1 folded)
    const _Float16* __restrict__ W2s,    // swizzled [(h>>3)][k][h&7]
    const float* __restrict__ b2,
    float* __restrict__ out) {           // [B*U*T][K]
    __shared__ __align__(16) _Float16 w_s[2][8192];  // 2 x 16 KB
    int tid = threadIdx.x, bid = blockIdx.x;
    int t0 = (bid & 7) * 64;
    int rest = bid >> 3;
    int u = rest % UU, b = rest / UU;
    int lane = tid & 63, wv = tid >> 6;  // 2 waves
    int lo = lane & 31, hi = lane >> 5;
    // this lane's h row: t0 + wv*32 + lo; k-cols: hi*8 + s*16 + {0..7}
    const _Float16* imgrow = imgHf + ((size_t)b * TT + t0 + wv * 32 + lo) * HH;
    const _Float16* labrow = labHf + (size_t)(b * UU + u) * HH;
    int kb = hi * 8;
    int ws_off = tid * 8;  // staging: 8 x f16x8 per thread per chunk
    floatx16 acc[4] = {};
    // prologue: async-stage chunk 0 W2 -> buf0; img/lab chunk 0 -> regs
#pragma unroll
    for (int i2 = 0; i2 < 8; ++i2)
        g2l16(&W2s[i2 * 1024 + ws_off], &w_s[0][i2 * 1024 + ws_off]);
    f16x8 iv[4], lv[4];
#pragma unroll
    for (int s = 0; s < 4; ++s) {
        iv[s] = *(const f16x8*)&imgrow[s * 16 + kb];
        lv[s] = *(const f16x8*)&labrow[s * 16 + kb];
    }
    __syncthreads();
#pragma unroll 2
    for (int c = 0; c < 16; ++c) {
        int buf = c & 1;
        // async-stage next W2 chunk into the other buffer (drains at barrier)
        if (c < 15) {
            const _Float16* wsrc = W2s + (size_t)(c + 1) * 8192;
#pragma unroll
            for (int i2 = 0; i2 < 8; ++i2)
                g2l16(&wsrc[i2 * 1024 + ws_off],
                      &w_s[buf ^ 1][i2 * 1024 + ws_off]);
        }
        // h = tanh(img + lab) -> A-frags for 4 k-steps
        f16x8 a[4];
#pragma unroll
        for (int s = 0; s < 4; ++s) a[s] = tanh8(iv[s] + lv[s]);
        // prefetch next img/lab into regs (hides under MFMA)
        if (c < 15) {
            int cb = (c + 1) * 64;
#pragma unroll
            for (int s = 0; s < 4; ++s) {
                iv[s] = *(const f16x8*)&imgrow[cb + s * 16 + kb];
                lv[s] = *(const f16x8*)&labrow[cb + s * 16 + kb];
            }
        }
#pragma unroll
        for (int s = 0; s < 4; ++s) {
#pragma unroll
            for (int ct = 0; ct < 4; ++ct) {
                f16x8 bf = *(const f16x8*)
                    &w_s[buf][((s * 2 + hi) * 128 + ct * 32 + lo) * 8];
                acc[ct] = __builtin_amdgcn_mfma_f32_32x32x16_f16(
                    a[s], bf, acc[ct], 0, 0, 0);
            }
        }
        __syncthreads();
    }
    // epilogue: +b2, per-row log-softmax (row data spread over 32 lanes x 4 regs)
    float b2v[4];
#pragma unroll
    for (int ct = 0; ct < 4; ++ct) b2v[ct] = b2[ct * 32 + lo];
    float* obase = out + (((size_t)b * UU + u) * TT + t0 + wv * 32) * KK;
#pragma unroll
    for (int reg = 0; reg < 16; ++reg) {
        int row = (reg & 3) + 8 * (reg >> 2) + 4 * hi;
        float v[4];
        float mx = -INFINITY;
#pragma unroll
        for (int ct = 0; ct < 4; ++ct) {
            v[ct] = acc[ct][reg] + b2v[ct];
            mx = fmaxf(mx, v[ct]);
        }
        mx = fmaxf(mx, __shfl_xor(mx, 1, 32));
        mx = fmaxf(mx, __shfl_xor(mx, 2, 32));
        mx = fmaxf(mx, __shfl_xor(mx, 4, 32));
        mx = fmaxf(mx, __shfl_xor(mx, 8, 32));
        mx = fmaxf(mx, __shfl_xor(mx, 16, 32));
        float s = 0.f;
#pragma unroll
        for (int ct = 0; ct < 4; ++ct) s += __expf(v[ct] - mx);
        s += __shfl_xor(s, 1, 32);
        s += __shfl_xor(s, 2, 32);
        s += __shfl_xor(s, 4, 32);
        s += __shfl_xor(s, 8, 32);
        s += __shfl_xor(s, 16, 32);
        float lse = mx + __logf(s);
#pragma unroll
        for (int ct = 0; ct < 4; ++ct)
            obase[(size_t)row * KK + ct * 32 + lo] = v[ct] - lse;
    }
}

extern "C" void kernel_launch(void* const* d_in, const int* in_sizes, int n_in,
                              void* d_out, int out_size, void* d_ws, size_t ws_size,
                              hipStream_t stream) {
    const float* img    = (const float*)d_in[0];
    const float* labf   = (const float*)d_in[1];
    const float* masks  = (const float*)d_in[2];
    const float* W1     = (const float*)d_in[3];
    const float* b1     = (const float*)d_in[4];
    const float* W2     = (const float*)d_in[5];
    const float* b2     = (const float*)d_in[6];
    const float* conv_w = (const float*)d_in[7];
    const float* conv_b = (const float*)d_in[8];
    float* out = (float*)d_out;

    _Float16* base  = (_Float16*)d_ws;
    _Float16* imgHf = base;                    // [1024][1024]
    _Float16* labHf = imgHf + 1024 * 1024;     // [96][1024]
    _Float16* W2s   = labHf + 96 * 1024;       // [H/8][K][8] = 131072

    mid_kernel4<<<328, 256, 0, stream>>>(img, labf, W1, W2, conv_w,
                                         b1, conv_b, masks,
                                         imgHf, labHf, W2s, out);
    joint_kernel9<<<768, 128, 0, stream>>>(imgHf, labHf, W2s, b2,
                                           out + (size_t)BB * KK * TT);
}

// Round 12
// 124.842 us; speedup vs baseline: 1.0727x; 1.0727x over previous
//
#include <hip/hip_runtime.h>
#include <math.h>

#define BB 2
#define TT 512
#define UU 48
#define DD 512
#define HH 1024
#define KK 128

typedef _Float16 f16x8 __attribute__((ext_vector_type(8)));
typedef __fp16 fp16x2_t __attribute__((ext_vector_type(2)));
typedef float floatx4 __attribute__((ext_vector_type(4)));

// async 16B/lane global->LDS (dest: wave-uniform base + lane*16)
__device__ __forceinline__ void g2l16(const _Float16* g, _Float16* l) {
    __builtin_amdgcn_global_load_lds(
        (const __attribute__((address_space(1))) unsigned int*)g,
        (__attribute__((address_space(3))) unsigned int*)l, 16, 0, 0);
}

// tanh(x) = 1 - 2/(e^{2x}+1). Safe at +-inf (no clamp).
__device__ __forceinline__ f16x8 tanh8(f16x8 x) {
    f16x8 o;
#pragma unroll
    for (int i = 0; i < 8; i += 2) {
        float s0 = (float)x[i];
        float s1 = (float)x[i + 1];
        float e0 = __expf(s0 + s0);
        float e1 = __expf(s1 + s1);
        float r0 = __builtin_amdgcn_rcpf(e0 + 1.0f);
        float r1 = __builtin_amdgcn_rcpf(e1 + 1.0f);
        fp16x2_t p = __builtin_amdgcn_cvt_pkrtz(fmaf(-2.0f, r0, 1.0f),
                                                fmaf(-2.0f, r1, 1.0f));
        o[i] = (_Float16)p[0];
        o[i + 1] = (_Float16)p[1];
    }
    return o;
}

// ---------------- mid: imgH/labH/seg GEMMs + W2 swizzle, one dispatch -------
__global__ __launch_bounds__(256) void mid_kernel4(
    const float* __restrict__ img, const float* __restrict__ labf,
    const float* __restrict__ W1, const float* __restrict__ W2,
    const float* __restrict__ conv_w,
    const float* __restrict__ b1, const float* __restrict__ conv_b,
    const float* __restrict__ masks,
    _Float16* __restrict__ imgHf, _Float16* __restrict__ labHf,
    _Float16* __restrict__ W2s, float* __restrict__ seg_out) {
    int bid = blockIdx.x, tid = threadIdx.x;
    if (bid >= 312) {  // W2 swizzle: W2s[(h>>3)*1024 + k*8 + (h&7)] = W2[k][h]
        int base = (bid - 312) * 256 + tid;
#pragma unroll
        for (int i = 0; i < 32; ++i) {
            int o = base + i * 4096;
            int hg = o >> 10, kk2 = (o >> 3) & 127, hl = o & 7;
            W2s[o] = (_Float16)W2[(size_t)kk2 * HH + hg * 8 + hl];
        }
        return;
    }
    __shared__ __align__(16) _Float16 a_s[32][72];
    __shared__ __align__(16) _Float16 w_s[8192];
    const float* Arow;
    const float* Wbase;
    int r0, n0b, wstride, region;
    if (bid < 256) {
        region = 0; Arow = img; Wbase = W1 + 512; wstride = 1024;
        r0 = (bid & 31) * 32; n0b = (bid >> 5) * 128;
    } else if (bid < 280) {
        region = 1; Arow = labf; Wbase = W1; wstride = 1024;
        int i = bid - 256; r0 = (i % 3) * 32; n0b = (i / 3) * 128;
    } else {
        region = 2; Arow = img; Wbase = conv_w; wstride = 512;
        r0 = (bid - 280) * 32; n0b = 0;
    }
    int lane = tid & 63, wv = tid >> 6;
    int m0 = (wv & 1) * 16, n0w = (wv >> 1) * 64;
    int q = lane >> 4, r = lane & 15;
    int arow = tid >> 3, acol = (tid & 7) * 8;
    int wn = tid >> 3, wk = tid & 7;
    const float* aptr = &Arow[(size_t)(r0 + arow) * DD + acol];
    floatx4 acc[4] = {};
    float4 pa0, pa1, pw[4][2];
    pa0 = *(const float4*)aptr;
    pa1 = *(const float4*)(aptr + 4);
#pragma unroll
    for (int i2 = 0; i2 < 4; ++i2) {
        const float* wp_ = &Wbase[(size_t)(n0b + i2 * 32 + wn) * wstride + wk * 8];
        pw[i2][0] = *(const float4*)wp_;
        pw[i2][1] = *(const float4*)(wp_ + 4);
    }
    for (int c = 0; c < 8; ++c) {
        {
            f16x8 av;
            av[0] = (_Float16)pa0.x; av[1] = (_Float16)pa0.y;
            av[2] = (_Float16)pa0.z; av[3] = (_Float16)pa0.w;
            av[4] = (_Float16)pa1.x; av[5] = (_Float16)pa1.y;
            av[6] = (_Float16)pa1.z; av[7] = (_Float16)pa1.w;
            *(f16x8*)&a_s[arow][acol] = av;
#pragma unroll
            for (int i2 = 0; i2 < 4; ++i2) {
                f16x8 wvv;
                wvv[0] = (_Float16)pw[i2][0].x; wvv[1] = (_Float16)pw[i2][0].y;
                wvv[2] = (_Float16)pw[i2][0].z; wvv[3] = (_Float16)pw[i2][0].w;
                wvv[4] = (_Float16)pw[i2][1].x; wvv[5] = (_Float16)pw[i2][1].y;
                wvv[6] = (_Float16)pw[i2][1].z; wvv[7] = (_Float16)pw[i2][1].w;
                *(f16x8*)&w_s[((size_t)wk * 128 + i2 * 32 + wn) * 8] = wvv;
            }
        }
        __syncthreads();
        if (c < 7) {
            int cb = (c + 1) * 64;
            pa0 = *(const float4*)(aptr + cb);
            pa1 = *(const float4*)(aptr + cb + 4);
#pragma unroll
            for (int i2 = 0; i2 < 4; ++i2) {
                const float* wp_ =
                    &Wbase[(size_t)(n0b + i2 * 32 + wn) * wstride + cb + wk * 8];
                pw[i2][0] = *(const float4*)wp_;
                pw[i2][1] = *(const float4*)(wp_ + 4);
            }
        }
#pragma unroll
        for (int kt = 0; kt < 2; ++kt) {
            f16x8 af = *(const f16x8*)&a_s[m0 + r][kt * 32 + q * 8];
#pragma unroll
            for (int nt = 0; nt < 4; ++nt) {
                f16x8 bfv = *(const f16x8*)
                    &w_s[((kt * 4 + q) * 128 + n0w + nt * 16 + r) * 8];
                acc[nt] = __builtin_amdgcn_mfma_f32_16x16x32_f16(
                    af, bfv, acc[nt], 0, 0, 0);
            }
        }
        __syncthreads();
    }
    if (region == 0) {
#pragma unroll
        for (int nt = 0; nt < 4; ++nt) {
            int n = n0b + n0w + nt * 16 + r;
#pragma unroll
            for (int rr = 0; rr < 4; ++rr)
                imgHf[(size_t)(r0 + m0 + 4 * q + rr) * HH + n] =
                    (_Float16)acc[nt][rr];
        }
    } else if (region == 1) {
#pragma unroll
        for (int nt = 0; nt < 4; ++nt) {
            int n = n0b + n0w + nt * 16 + r;
            float bv = b1[n];
#pragma unroll
            for (int rr = 0; rr < 4; ++rr)
                labHf[(size_t)(r0 + m0 + 4 * q + rr) * HH + n] =
                    (_Float16)(acc[nt][rr] + bv);
        }
    } else {
#pragma unroll
        for (int nt = 0; nt < 4; ++nt) {
            int k = n0w + nt * 16 + r;
            float bv = conv_b[k];
#pragma unroll
            for (int rr = 0; rr < 4; ++rr) {
                int row = r0 + m0 + 4 * q + rr;
                int b = row >> 9, t = row & 511;
                seg_out[((size_t)b * KK + k) * TT + t] =
                    (acc[nt][rr] + bv) * masks[row];
            }
        }
    }
}

// ---------------- joint: zero-LDS h, W2 via depth-2 async g2l pipeline over
// 3 rotating LDS buffers; every VMEM op drains a full chunk after issue.
__global__ __launch_bounds__(256) void joint_kernel10(
    const _Float16* __restrict__ imgHf,  // [B*T][H]
    const _Float16* __restrict__ labHf,  // [B*U][H] (b1 folded)
    const _Float16* __restrict__ W2s,    // swizzled [(h>>3)][k][h&7]
    const float* __restrict__ b2,
    float* __restrict__ out) {           // [B*U*T][K]
    __shared__ __align__(16) _Float16 w_s[3][8192];  // 3 x 16 KB rotating
    int tid = threadIdx.x, bid = blockIdx.x;
    int t0 = (bid & 7) * 64;
    int rest = bid >> 3;
    int u = rest % UU, b = rest / UU;
    int lane = tid & 63, wv = tid >> 6;
    int q = lane >> 4, r = lane & 15;
    const _Float16* imgrow = imgHf + ((size_t)b * TT + t0 + wv * 16 + r) * HH;
    const _Float16* labrow = labHf + (size_t)(b * UU + u) * HH;
    int c0 = q * 8, c1 = 32 + q * 8;
    int ws_off = tid * 8;  // 16B per lane, lane-contiguous per wave
    floatx4 acc[8] = {};
    // prologue: async-stage chunks 0,1 -> buf0,buf1; img/lab chunk 0 -> regs
#pragma unroll
    for (int i2 = 0; i2 < 4; ++i2)
        g2l16(&W2s[i2 * 2048 + ws_off], &w_s[0][i2 * 2048 + ws_off]);
#pragma unroll
    for (int i2 = 0; i2 < 4; ++i2)
        g2l16(&W2s[8192 + i2 * 2048 + ws_off], &w_s[1][i2 * 2048 + ws_off]);
    f16x8 ivA = *(const f16x8*)&imgrow[c0];
    f16x8 ivB = *(const f16x8*)&imgrow[c1];
    f16x8 lvA = *(const f16x8*)&labrow[c0];
    f16x8 lvB = *(const f16x8*)&labrow[c1];
    __syncthreads();
    int cur = 0;   // buffer holding chunk c
    int wt = 2;    // buffer to write chunk c+2 into
#pragma unroll 4
    for (int c = 0; c < 16; ++c) {
        // issue next-next W2 stage and next img/lab prefetch FIRST:
        // they have the whole chunk to drain before the barrier.
        if (c < 14) {
            const _Float16* wsrc = W2s + (size_t)(c + 2) * 8192;
#pragma unroll
            for (int i2 = 0; i2 < 4; ++i2)
                g2l16(&wsrc[i2 * 2048 + ws_off],
                      &w_s[wt][i2 * 2048 + ws_off]);
        }
        f16x8 nivA, nivB, nlvA, nlvB;
        if (c < 15) {
            int cb = (c + 1) * 64;
            nivA = *(const f16x8*)&imgrow[cb + c0];
            nivB = *(const f16x8*)&imgrow[cb + c1];
            nlvA = *(const f16x8*)&labrow[cb + c0];
            nlvB = *(const f16x8*)&labrow[cb + c1];
        }
        // h = tanh(img + lab): packed f16 add, exp-tanh, straight into A-frags
        f16x8 a0 = tanh8(ivA + lvA);
        f16x8 a1 = tanh8(ivB + lvB);
#pragma unroll
        for (int nt = 0; nt < 8; ++nt) {
            f16x8 bf0 = *(const f16x8*)&w_s[cur][((0 + q) * 128 + nt * 16 + r) * 8];
            acc[nt] = __builtin_amdgcn_mfma_f32_16x16x32_f16(
                a0, bf0, acc[nt], 0, 0, 0);
        }
#pragma unroll
        for (int nt = 0; nt < 8; ++nt) {
            f16x8 bf1 = *(const f16x8*)&w_s[cur][((4 + q) * 128 + nt * 16 + r) * 8];
            acc[nt] = __builtin_amdgcn_mfma_f32_16x16x32_f16(
                a1, bf1, acc[nt], 0, 0, 0);
        }
        if (c < 15) { ivA = nivA; ivB = nivB; lvA = nlvA; lvB = nlvB; }
        cur = (cur == 2) ? 0 : cur + 1;
        wt = (wt == 2) ? 0 : wt + 1;
        __syncthreads();
    }
    // epilogue: +b2, in-register log-softmax over this 16-lane group's 128 cols
    float b2v[8];
#pragma unroll
    for (int nt = 0; nt < 8; ++nt) b2v[nt] = b2[nt * 16 + r];
    float* orow = out + (((size_t)b * UU + u) * TT + t0 + wv * 16) * KK;
#pragma unroll
    for (int rr = 0; rr < 4; ++rr) {
        float v[8];
        float mx = -INFINITY;
#pragma unroll
        for (int nt = 0; nt < 8; ++nt) {
            v[nt] = acc[nt][rr] + b2v[nt];
            mx = fmaxf(mx, v[nt]);
        }
        mx = fmaxf(mx, __shfl_xor(mx, 1, 16));
        mx = fmaxf(mx, __shfl_xor(mx, 2, 16));
        mx = fmaxf(mx, __shfl_xor(mx, 4, 16));
        mx = fmaxf(mx, __shfl_xor(mx, 8, 16));
        float s = 0.f;
#pragma unroll
        for (int nt = 0; nt < 8; ++nt) s += __expf(v[nt] - mx);
        s += __shfl_xor(s, 1, 16);
        s += __shfl_xor(s, 2, 16);
        s += __shfl_xor(s, 4, 16);
        s += __shfl_xor(s, 8, 16);
        float lse = mx + __logf(s);
        int row = 4 * q + rr;
#pragma unroll
        for (int nt = 0; nt < 8; ++nt)
            orow[(size_t)row * KK + nt * 16 + r] = v[nt] - lse;
    }
}

extern "C" void kernel_launch(void* const* d_in, const int* in_sizes, int n_in,
                              void* d_out, int out_size, void* d_ws, size_t ws_size,
                              hipStream_t stream) {
    const float* img    = (const float*)d_in[0];
    const float* labf   = (const float*)d_in[1];
    const float* masks  = (const float*)d_in[2];
    const float* W1     = (const float*)d_in[3];
    const float* b1     = (const float*)d_in[4];
    const float* W2     = (const float*)d_in[5];
    const float* b2     = (const float*)d_in[6];
    const float* conv_w = (const float*)d_in[7];
    const float* conv_b = (const float*)d_in[8];
    float* out = (float*)d_out;

    _Float16* base  = (_Float16*)d_ws;
    _Float16* imgHf = base;                    // [1024][1024]
    _Float16* labHf = imgHf + 1024 * 1024;     // [96][1024]
    _Float16* W2s   = labHf + 96 * 1024;       // [H/8][K][8] = 131072

    mid_kernel4<<<328, 256, 0, stream>>>(img, labf, W1, W2, conv_w,
                                         b1, conv_b, masks,
                                         imgHf, labHf, W2s, out);
    joint_kernel10<<<768, 256, 0, stream>>>(imgHf, labHf, W2s, b2,
                                            out + (size_t)BB * KK * TT);
}